// Round 2
// baseline (183.196 us; speedup 1.0000x reference)
//
#include <hip/hip_runtime.h>

// Problem constants (match reference)
#define BATCH  8192
#define KK     25
#define LL     25
#define BN_EPS 1e-5f
#define PREPB  32              // prep blocks (256 rows each) — R6 proven
#define LG     5               // l-values per eval block
#define NLG    (LL / LG)
#define VB     4               // batch elements per thread in eval (R12: back to R10 value)
#define EVT    256             // eval block threads
#define NBX    (BATCH / (EVT * VB))   // 8 batch-blocks
#define WSP    80              // per-l LDS packed-weight slab stride (dwords)

// Workspace layout (float offsets):
#define WS_PART   0                         // [PREPB][50] partial sums
#define WS_SCALE  1600                      // (fallback path only)
#define WS_SHIFT  1632
#define WS_CNT    1700                      // [NBX*KK] int tickets (R12 fused reduce)
#define WS_XT     2048                      // [LL][BATCH] transposed x
#define WS_FP     (WS_XT + LL * BATCH)      // [NLG][KK][BATCH] partial outputs
#define WS_END    (WS_FP + NLG * KK * BATCH)

// Packed fp16 pair in one VGPR. R10: weights stored as (w[2p], w[2p+1]) —
// two DIFFERENT weights per dword — and broadcast into both batch lanes via
// VOP3P op_sel modifiers. R12: reduce kernel fused into eval via a
// last-arriver ticket (split-K pattern): the 5th g-block per (bx,k) sums the
// other partials and writes out directly. Removes one dispatch + 4MB re-read.
typedef _Float16 h2v __attribute__((ext_vector_type(2)));

// d.lane = fma(a.lane, w.lo, c.lane)
static __device__ __forceinline__ h2v pk_fma_wl(h2v a, h2v w, h2v c) {
    h2v d;
    asm("v_pk_fma_f16 %0, %1, %2, %3 op_sel:[0,0,0] op_sel_hi:[1,0,1]"
        : "=v"(d) : "v"(a), "v"(w), "v"(c));
    return d;
}
// d.lane = fma(a.lane, w.hi, c.lane)
static __device__ __forceinline__ h2v pk_fma_wh(h2v a, h2v w, h2v c) {
    h2v d;
    asm("v_pk_fma_f16 %0, %1, %2, %3 op_sel:[0,1,0] op_sel_hi:[1,1,1]"
        : "=v"(d) : "v"(a), "v"(w), "v"(c));
    return d;
}
// d.lane = fma(a.lane, w.lo, c.lo)
static __device__ __forceinline__ h2v pk_fma_wl_cl(h2v a, h2v w, h2v c) {
    h2v d;
    asm("v_pk_fma_f16 %0, %1, %2, %3 op_sel:[0,0,0] op_sel_hi:[1,0,0]"
        : "=v"(d) : "v"(a), "v"(w), "v"(c));
    return d;
}
// d.lane = fma(a.lane, w.lo, c.hi)
static __device__ __forceinline__ h2v pk_fma_wl_ch(h2v a, h2v w, h2v c) {
    h2v d;
    asm("v_pk_fma_f16 %0, %1, %2, %3 op_sel:[0,0,1] op_sel_hi:[1,0,1]"
        : "=v"(d) : "v"(a), "v"(w), "v"(c));
    return d;
}
// d.lane = fma(a.lane, w.hi, c.hi)
static __device__ __forceinline__ h2v pk_fma_wh_ch(h2v a, h2v w, h2v c) {
    h2v d;
    asm("v_pk_fma_f16 %0, %1, %2, %3 op_sel:[0,1,1] op_sel_hi:[1,1,1]"
        : "=v"(d) : "v"(a), "v"(w), "v"(c));
    return d;
}
static __device__ __forceinline__ h2v pk_max(h2v a, h2v b) {
    h2v d;
    asm("v_pk_max_f16 %0, %1, %2" : "=v"(d) : "v"(a), "v"(b));
    return d;
}
static __device__ __forceinline__ h2v pack2(float a, float b) {
    h2v r; r.x = (_Float16)a; r.y = (_Float16)b; return r;
}

// ---------------------------------------------------------------------------
// prep: coalesced read of x chunk -> LDS; coalesced transposed write to xT;
// per-column partial sum/sumsq (no atomics). 32 blocks x 256 rows.
// R12: block 0 additionally zeroes the eval ticket counters (ws is poisoned).
// ---------------------------------------------------------------------------
__global__ __launch_bounds__(256) void prep_kernel(
    const float* __restrict__ x,
    float* __restrict__ xT,
    float* __restrict__ part)
{
    __shared__ float xs[256 * LL];          // 25.6 KB
    const int tid = threadIdx.x;
    const int b0  = blockIdx.x * 256;

    if (blockIdx.x == 0 && tid < NBX * KK)
        ((int*)part)[WS_CNT + tid] = 0;     // part == ws base

    const float* src = x + (size_t)b0 * LL;
    #pragma unroll
    for (int i = 0; i < LL; ++i)
        xs[i * 256 + tid] = src[i * 256 + tid];
    __syncthreads();

    #pragma unroll
    for (int l = 0; l < LL; ++l)
        xT[l * BATCH + b0 + tid] = xs[tid * LL + l];

    float s = 0.f, s2 = 0.f;
    if (tid < 200) {
        const int l = tid % LL;
        const int g = tid / LL;
        #pragma unroll
        for (int r = 0; r < 32; ++r) {
            const float v = xs[(g * 32 + r) * LL + l];
            s += v;
            s2 = fmaf(v, v, s2);
        }
    }
    __syncthreads();
    if (tid < 200) { xs[tid] = s; xs[200 + tid] = s2; }
    __syncthreads();

    if (tid < 50) {
        const int c = tid;
        float t = 0.f;
        if (c < LL) {
            #pragma unroll
            for (int g = 0; g < 8; ++g) t += xs[g * LL + c];
        } else {
            #pragma unroll
            for (int g = 0; g < 8; ++g) t += xs[200 + g * LL + (c - LL)];
        }
        part[blockIdx.x * 50 + c] = t;
    }
}

// ---------------------------------------------------------------------------
// eval (R12): R10 packed-pair fp16 body (VB=4, 256 thr) + fused final reduce.
// Each block writes its g-partial to fp, releases with __threadfence, takes a
// ticket on cnt[bx*KK+k]; the last arriver (ticket==NLG-1) acquires, sums the
// other 4 partials (volatile = L1-bypass) + own registers + beta, writes out.
// LDS slab per j (stride WSP=80 dwords):
//   [0:4) w1p [4:8) b1p [8:40) w2p [40:44) b2p [44:68) w3p [68:71) b3p [71:74) w4p
//   pair p of array A holds (A[2p], A[2p+1]).
// ---------------------------------------------------------------------------
__global__ __launch_bounds__(256) void eval_kernel(
    const float* __restrict__ xT,
    const float* __restrict__ W1, const float* __restrict__ b1,
    const float* __restrict__ W2, const float* __restrict__ b2,
    const float* __restrict__ W3, const float* __restrict__ b3,
    const float* __restrict__ W4, const float* __restrict__ b4,
    const float* __restrict__ alpha,
    const float* __restrict__ part,
    const float* __restrict__ gamma,
    const float* __restrict__ bn_bias,
    const float* __restrict__ beta,
    float* __restrict__ fp,
    int*   __restrict__ cnt,
    float* __restrict__ out)
{
    __shared__ h2v   wl[LG * WSP];          // 400 dwords = 1.6 KB
    __shared__ float sss[2 * LG];           // scale[5], shift[5] (fp32)
    __shared__ float tmp[2 * LG];
    __shared__ int   lastflag;

    const int tid = threadIdx.x;
    const int k   = blockIdx.y;
    const int g   = blockIdx.z;
    const int l0  = g * LG;
    const int kl0 = k * LL + l0;
    const int b   = (blockIdx.x * EVT + tid) * VB;

    // ---- stage weights as packed pairs (once per block) ----
    if (tid < 160) {                         // w2p: 5*32
        const int j = tid >> 5, p = tid & 31;
        const float* s = W2 + (kl0 + j) * 64 + 2 * p;
        wl[j * WSP + 8 + p] = pack2(s[0], s[1]);
    }
    if (tid < 120) {                         // w3p: 5*24
        const int j = tid / 24, p = tid % 24;
        const float* s = W3 + (kl0 + j) * 48 + 2 * p;
        wl[j * WSP + 44 + p] = pack2(s[0], s[1]);
    }
    if (tid < 20) {                          // w1p, b1p, b2p: 5*4 each
        const int j = tid >> 2, p = tid & 3;
        const float* s1 = W1 + (kl0 + j) * 8 + 2 * p;
        const float* t1 = b1 + (kl0 + j) * 8 + 2 * p;
        const float* t2 = b2 + (kl0 + j) * 8 + 2 * p;
        wl[j * WSP +      p] = pack2(s1[0], s1[1]);
        wl[j * WSP +  4 + p] = pack2(t1[0], t1[1]);
        wl[j * WSP + 40 + p] = pack2(t2[0], t2[1]);
    }
    if (tid < 15) {                          // b3p, w4p: 5*3 each
        const int j = tid / 3, p = tid % 3;
        const float* t3 = b3 + (kl0 + j) * 6 + 2 * p;
        const float* s4 = W4 + (kl0 + j) * 6 + 2 * p;
        wl[j * WSP + 68 + p] = pack2(t3[0], t3[1]);
        wl[j * WSP + 71 + p] = pack2(s4[0], s4[1]);
    }

    // ---- stats preamble: reduce prep partials for this block's columns ----
    if (tid >= 128 && tid < 128 + 2 * LG) {
        const int t2  = tid - 128;                      // 0..9
        const int col = (t2 < LG) ? (l0 + t2) : (LL + l0 + t2 - LG);
        float s = 0.f;
        #pragma unroll
        for (int i = 0; i < PREPB; ++i)
            s += part[i * 50 + col];
        tmp[t2] = s;
    }
    __syncthreads();
    if (tid < LG) {
        const float s = tmp[tid], s2 = tmp[LG + tid];
        const float inv_b = 1.f / (float)BATCH;
        const float mean  = s * inv_b;
        const float var   = fmaf(s2, inv_b, -mean * mean);
        const float scale = rsqrtf(var + BN_EPS) * gamma[l0 + tid];
        sss[tid]      = scale;
        sss[LG + tid] = fmaf(-mean, scale, bn_bias[l0 + tid]);
    }
    __syncthreads();

    // ---- compute (packed fp16, op_sel weight broadcast) ----
    h2v zero2; zero2.x = (_Float16)0.f; zero2.y = (_Float16)0.f;
    float acc[VB] = {0.f, 0.f, 0.f, 0.f};

    #pragma unroll
    for (int j = 0; j < LG; ++j) {
        const int l = l0 + j;
        const h2v* w = wl + j * WSP;

        const float scale = sss[j];
        const float shift = sss[LG + j];
        const float a     = alpha[l * KK + k];        // wave-uniform s_load
        const float b4f   = b4[kl0 + j];              // wave-uniform s_load

        const float4 xv = *(const float4*)&xT[l * BATCH + b];
        h2v xn0, xn1;
        xn0.x = (_Float16)fmaf(xv.x, scale, shift);
        xn0.y = (_Float16)fmaf(xv.y, scale, shift);
        xn1.x = (_Float16)fmaf(xv.z, scale, shift);
        xn1.y = (_Float16)fmaf(xv.w, scale, shift);

        // layer 1: 1 -> 8  (w1p[p]=(w1[2p],w1[2p+1]), b1p same)
        h2v h1a[8], h1b[8];
        #pragma unroll
        for (int p = 0; p < 4; ++p) {
            const h2v wp = w[p], bp = w[4 + p];
            h1a[2*p]   = pk_max(pk_fma_wl_cl(xn0, wp, bp), zero2);
            h1a[2*p+1] = pk_max(pk_fma_wh_ch(xn0, wp, bp), zero2);
            h1b[2*p]   = pk_max(pk_fma_wl_cl(xn1, wp, bp), zero2);
            h1b[2*p+1] = pk_max(pk_fma_wh_ch(xn1, wp, bp), zero2);
        }

        // layer 2: 8 -> 8  (w2p[i*4+hp]=(w2[i*8+2hp], w2[i*8+2hp+1]))
        h2v h2a[8], h2b[8];
        #pragma unroll
        for (int i = 0; i < 8; ++i) {
            const h2v bp = w[40 + (i >> 1)];
            const h2v w0 = w[8 + i * 4];
            h2v t0, t1;
            if (i & 1) { t0 = pk_fma_wl_ch(h1a[0], w0, bp);
                         t1 = pk_fma_wl_ch(h1b[0], w0, bp); }
            else       { t0 = pk_fma_wl_cl(h1a[0], w0, bp);
                         t1 = pk_fma_wl_cl(h1b[0], w0, bp); }
            t0 = pk_fma_wh(h1a[1], w0, t0);
            t1 = pk_fma_wh(h1b[1], w0, t1);
            #pragma unroll
            for (int hp = 1; hp < 4; ++hp) {
                const h2v wp = w[8 + i * 4 + hp];
                t0 = pk_fma_wl(h1a[2*hp],   wp, t0);
                t1 = pk_fma_wl(h1b[2*hp],   wp, t1);
                t0 = pk_fma_wh(h1a[2*hp+1], wp, t0);
                t1 = pk_fma_wh(h1b[2*hp+1], wp, t1);
            }
            h2a[i] = pk_max(t0, zero2);
            h2b[i] = pk_max(t1, zero2);
        }

        // layer 3: 8 -> 6  (w3p[jj*4+ip])
        h2v h3a[6], h3b[6];
        #pragma unroll
        for (int jj = 0; jj < 6; ++jj) {
            const h2v bp = w[68 + (jj >> 1)];
            const h2v w0 = w[44 + jj * 4];
            h2v t0, t1;
            if (jj & 1) { t0 = pk_fma_wl_ch(h2a[0], w0, bp);
                          t1 = pk_fma_wl_ch(h2b[0], w0, bp); }
            else        { t0 = pk_fma_wl_cl(h2a[0], w0, bp);
                          t1 = pk_fma_wl_cl(h2b[0], w0, bp); }
            t0 = pk_fma_wh(h2a[1], w0, t0);
            t1 = pk_fma_wh(h2b[1], w0, t1);
            #pragma unroll
            for (int ip = 1; ip < 4; ++ip) {
                const h2v wp = w[44 + jj * 4 + ip];
                t0 = pk_fma_wl(h2a[2*ip],   wp, t0);
                t1 = pk_fma_wl(h2b[2*ip],   wp, t1);
                t0 = pk_fma_wh(h2a[2*ip+1], wp, t0);
                t1 = pk_fma_wh(h2b[2*ip+1], wp, t1);
            }
            h3a[jj] = pk_max(t0, zero2);
            h3b[jj] = pk_max(t1, zero2);
        }

        // layer 4: 6 -> 1 (w4p[jp]=(w4[2jp],w4[2jp+1])), finish in fp32
        h2v fd0 = zero2, fd1 = zero2;
        #pragma unroll
        for (int jp = 0; jp < 3; ++jp) {
            const h2v wp = w[71 + jp];
            fd0 = pk_fma_wl(h3a[2*jp],   wp, fd0);
            fd1 = pk_fma_wl(h3b[2*jp],   wp, fd1);
            fd0 = pk_fma_wh(h3a[2*jp+1], wp, fd0);
            fd1 = pk_fma_wh(h3b[2*jp+1], wp, fd1);
        }
        acc[0] = fmaf(a, b4f + (float)fd0.x, acc[0]);
        acc[1] = fmaf(a, b4f + (float)fd0.y, acc[1]);
        acc[2] = fmaf(a, b4f + (float)fd1.x, acc[2]);
        acc[3] = fmaf(a, b4f + (float)fd1.y, acc[3]);
    }

    // ---- publish partial, take ticket; last arriver finishes out ----
    float4 o = {acc[0], acc[1], acc[2], acc[3]};
    *(float4*)&fp[((size_t)g * KK + k) * BATCH + b] = o;

    __threadfence();                           // release fp writes (device scope)
    if (tid == 0)
        lastflag = (atomicAdd(&cnt[blockIdx.x * KK + k], 1) == NLG - 1);
    __syncthreads();

    if (lastflag) {
        __threadfence();                       // acquire other blocks' fp writes
        float s0 = acc[0], s1 = acc[1], s2 = acc[2], s3 = acc[3];
        #pragma unroll
        for (int gg = 0; gg < NLG; ++gg) {
            if (gg == g) continue;
            const volatile float* src = fp + ((size_t)gg * KK + k) * BATCH + b;
            s0 += src[0]; s1 += src[1]; s2 += src[2]; s3 += src[3];
        }
        const float bk = beta[k];
        float* dst = out + (size_t)b * KK + k;
        dst[0]      = bk + s0;
        dst[KK]     = bk + s1;
        dst[2 * KK] = bk + s2;
        dst[3 * KK] = bk + s3;
    }
}

// ---------------------------------------------------------------------------
// fallbacks (small workspace) — fp32, proven correct.
// ---------------------------------------------------------------------------
__device__ __forceinline__ float mlp_eval(
    float xn, int kl,
    const float* __restrict__ W1, const float* __restrict__ b1,
    const float* __restrict__ W2, const float* __restrict__ b2,
    const float* __restrict__ W3, const float* __restrict__ b3,
    const float* __restrict__ W4, const float* __restrict__ b4)
{
    const float* w1  = W1 + kl * 8;
    const float* bb1 = b1 + kl * 8;
    float h1[8];
    #pragma unroll
    for (int h = 0; h < 8; ++h)
        h1[h] = fmaxf(fmaf(xn, w1[h], bb1[h]), 0.f);

    const float* w2  = W2 + kl * 64;
    const float* bb2 = b2 + kl * 8;
    float h2v_[8];
    #pragma unroll
    for (int i = 0; i < 8; ++i) {
        float t = bb2[i];
        #pragma unroll
        for (int h = 0; h < 8; ++h)
            t = fmaf(h1[h], w2[i * 8 + h], t);
        h2v_[i] = fmaxf(t, 0.f);
    }

    const float* w3  = W3 + kl * 48;
    const float* bb3 = b3 + kl * 6;
    float h3[6];
    #pragma unroll
    for (int j = 0; j < 6; ++j) {
        float t = bb3[j];
        #pragma unroll
        for (int i = 0; i < 8; ++i)
            t = fmaf(h2v_[i], w3[j * 8 + i], t);
        h3[j] = fmaxf(t, 0.f);
    }

    const float* w4 = W4 + kl * 6;
    float f = b4[kl];
    #pragma unroll
    for (int j = 0; j < 6; ++j)
        f = fmaf(h3[j], w4[j], f);
    return f;
}

__global__ __launch_bounds__(256) void stats_small_kernel(
    const float* __restrict__ x,
    const float* __restrict__ gamma,
    const float* __restrict__ bn_bias,
    float* __restrict__ ws)
{
    const int l   = blockIdx.x;
    const int tid = threadIdx.x;

    float s = 0.f, s2 = 0.f;
    for (int b = tid; b < BATCH; b += 256) {
        float v = x[b * LL + l];
        s  += v;
        s2  = fmaf(v, v, s2);
    }
    for (int off = 32; off > 0; off >>= 1) {
        s  += __shfl_down(s,  off);
        s2 += __shfl_down(s2, off);
    }
    __shared__ float red[8];
    const int wave = tid >> 6;
    if ((tid & 63) == 0) { red[wave] = s; red[4 + wave] = s2; }
    __syncthreads();
    if (tid == 0) {
        s  = red[0] + red[1] + red[2] + red[3];
        s2 = red[4] + red[5] + red[6] + red[7];
        const float inv_b = 1.f / (float)BATCH;
        float mean = s * inv_b;
        float var  = fmaf(s2, inv_b, -mean * mean);
        float scale = rsqrtf(var + BN_EPS) * gamma[l];
        ws[WS_SCALE + l] = scale;
        ws[WS_SHIFT + l] = fmaf(-mean, scale, bn_bias[l]);
    }
}

__global__ __launch_bounds__(256) void mlp_lds_direct_kernel(
    const float* __restrict__ x,
    const float* __restrict__ W1, const float* __restrict__ b1,
    const float* __restrict__ W2, const float* __restrict__ b2,
    const float* __restrict__ W3, const float* __restrict__ b3,
    const float* __restrict__ W4, const float* __restrict__ b4,
    const float* __restrict__ alpha, const float* __restrict__ beta,
    const float* __restrict__ ws,
    float* __restrict__ out)
{
    __shared__ float xs[256 * LL];
    const int tid = threadIdx.x;
    const int k   = blockIdx.y;
    const int b0  = blockIdx.x * 256;

    const float* xsrc = x + (size_t)b0 * LL;
    #pragma unroll
    for (int i = 0; i < LL; ++i)
        xs[i * 256 + tid] = xsrc[i * 256 + tid];
    __syncthreads();

    float acc = beta[k];
    for (int l = 0; l < LL; ++l) {
        const int kl = k * LL + l;
        const float xn = fmaf(xs[tid * LL + l], ws[WS_SCALE + l], ws[WS_SHIFT + l]);
        const float f  = mlp_eval(xn, kl, W1, b1, W2, b2, W3, b3, W4, b4);
        acc = fmaf(alpha[l * KK + k], f, acc);
    }
    out[(size_t)(b0 + tid) * KK + k] = acc;
}

extern "C" void kernel_launch(void* const* d_in, const int* in_sizes, int n_in,
                              void* d_out, int out_size, void* d_ws, size_t ws_size,
                              hipStream_t stream) {
    const float* x       = (const float*)d_in[0];
    const float* gamma   = (const float*)d_in[1];
    const float* bn_bias = (const float*)d_in[2];
    const float* W1      = (const float*)d_in[3];
    const float* b1      = (const float*)d_in[4];
    const float* W2      = (const float*)d_in[5];
    const float* b2      = (const float*)d_in[6];
    const float* W3      = (const float*)d_in[7];
    const float* b3      = (const float*)d_in[8];
    const float* W4      = (const float*)d_in[9];
    const float* b4      = (const float*)d_in[10];
    const float* alpha   = (const float*)d_in[11];
    const float* beta    = (const float*)d_in[12];

    float* out = (float*)d_out;
    float* ws  = (float*)d_ws;
    float* xT  = ws + WS_XT;
    float* fp  = ws + WS_FP;
    int*   cnt = (int*)ws + WS_CNT;

    const bool fast = ws_size >= (size_t)WS_END * sizeof(float);

    if (fast) {
        prep_kernel<<<dim3(PREPB), dim3(256), 0, stream>>>(x, xT, ws + WS_PART);
        eval_kernel<<<dim3(NBX, KK, NLG), dim3(EVT), 0, stream>>>(
            xT, W1, b1, W2, b2, W3, b3, W4, b4, alpha,
            ws + WS_PART, gamma, bn_bias, beta, fp, cnt, out);
    } else {
        stats_small_kernel<<<dim3(LL), dim3(256), 0, stream>>>(x, gamma, bn_bias, ws);
        mlp_lds_direct_kernel<<<dim3(BATCH / 256, KK), dim3(256), 0, stream>>>(
            x, W1, b1, W2, b2, W3, b3, W4, b4, alpha, beta, ws, out);
    }
}

// Round 3
// 130.635 us; speedup vs baseline: 1.4023x; 1.4023x over previous
//
#include <hip/hip_runtime.h>

// Problem constants (match reference)
#define BATCH  8192
#define KK     25
#define LL     25
#define BN_EPS 1e-5f
#define PREPB  32              // prep blocks (256 rows each) — R6 proven
#define VB     4               // batch elements per thread in eval
#define EVT    256             // eval block threads
#define NBX    (BATCH / (EVT * VB))   // 8 batch-blocks
#define WSP    80              // per-l LDS packed-weight slab stride (dwords)

// Workspace layout (float offsets):
#define WS_PART   0                         // [PREPB][50] partial sums
#define WS_SCALE  1600                      // (fallback path only)
#define WS_SHIFT  1632
#define WS_XT     2048                      // [LL][BATCH] transposed x
#define WS_END    (WS_XT + LL * BATCH)

// Packed fp16 pair in one VGPR: weights stored as (w[2p], w[2p+1]) — two
// DIFFERENT weights per dword — broadcast per-half via VOP3P op_sel (R10).
// R13: mono-eval. Each block owns (bx, k) and runs ALL 25 l's, accumulating
// in registers; out written directly. This removes the reduce dispatch, its
// launch gap, and the 9.6 MB fp round-trip WITHOUT any device-scope fence
// (R12's __threadfence per block cost ~100 µs in L2 maintenance — reverted).
typedef _Float16 h2v __attribute__((ext_vector_type(2)));

// d.lane = fma(a.lane, w.lo, c.lane)
static __device__ __forceinline__ h2v pk_fma_wl(h2v a, h2v w, h2v c) {
    h2v d;
    asm("v_pk_fma_f16 %0, %1, %2, %3 op_sel:[0,0,0] op_sel_hi:[1,0,1]"
        : "=v"(d) : "v"(a), "v"(w), "v"(c));
    return d;
}
// d.lane = fma(a.lane, w.hi, c.lane)
static __device__ __forceinline__ h2v pk_fma_wh(h2v a, h2v w, h2v c) {
    h2v d;
    asm("v_pk_fma_f16 %0, %1, %2, %3 op_sel:[0,1,0] op_sel_hi:[1,1,1]"
        : "=v"(d) : "v"(a), "v"(w), "v"(c));
    return d;
}
// d.lane = fma(a.lane, w.lo, c.lo)
static __device__ __forceinline__ h2v pk_fma_wl_cl(h2v a, h2v w, h2v c) {
    h2v d;
    asm("v_pk_fma_f16 %0, %1, %2, %3 op_sel:[0,0,0] op_sel_hi:[1,0,0]"
        : "=v"(d) : "v"(a), "v"(w), "v"(c));
    return d;
}
// d.lane = fma(a.lane, w.lo, c.hi)
static __device__ __forceinline__ h2v pk_fma_wl_ch(h2v a, h2v w, h2v c) {
    h2v d;
    asm("v_pk_fma_f16 %0, %1, %2, %3 op_sel:[0,0,1] op_sel_hi:[1,0,1]"
        : "=v"(d) : "v"(a), "v"(w), "v"(c));
    return d;
}
// d.lane = fma(a.lane, w.hi, c.hi)
static __device__ __forceinline__ h2v pk_fma_wh_ch(h2v a, h2v w, h2v c) {
    h2v d;
    asm("v_pk_fma_f16 %0, %1, %2, %3 op_sel:[0,1,1] op_sel_hi:[1,1,1]"
        : "=v"(d) : "v"(a), "v"(w), "v"(c));
    return d;
}
static __device__ __forceinline__ h2v pk_max(h2v a, h2v b) {
    h2v d;
    asm("v_pk_max_f16 %0, %1, %2" : "=v"(d) : "v"(a), "v"(b));
    return d;
}
static __device__ __forceinline__ h2v pack2(float a, float b) {
    h2v r; r.x = (_Float16)a; r.y = (_Float16)b; return r;
}

// ---------------------------------------------------------------------------
// prep: coalesced read of x chunk -> LDS; coalesced transposed write to xT;
// per-column partial sum/sumsq (no atomics). 32 blocks x 256 rows. (R6 verbatim)
// ---------------------------------------------------------------------------
__global__ __launch_bounds__(256) void prep_kernel(
    const float* __restrict__ x,
    float* __restrict__ xT,
    float* __restrict__ part)
{
    __shared__ float xs[256 * LL];          // 25.6 KB
    const int tid = threadIdx.x;
    const int b0  = blockIdx.x * 256;

    const float* src = x + (size_t)b0 * LL;
    #pragma unroll
    for (int i = 0; i < LL; ++i)
        xs[i * 256 + tid] = src[i * 256 + tid];
    __syncthreads();

    #pragma unroll
    for (int l = 0; l < LL; ++l)
        xT[l * BATCH + b0 + tid] = xs[tid * LL + l];

    float s = 0.f, s2 = 0.f;
    if (tid < 200) {
        const int l = tid % LL;
        const int g = tid / LL;
        #pragma unroll
        for (int r = 0; r < 32; ++r) {
            const float v = xs[(g * 32 + r) * LL + l];
            s += v;
            s2 = fmaf(v, v, s2);
        }
    }
    __syncthreads();
    if (tid < 200) { xs[tid] = s; xs[200 + tid] = s2; }
    __syncthreads();

    if (tid < 50) {
        const int c = tid;
        float t = 0.f;
        if (c < LL) {
            #pragma unroll
            for (int g = 0; g < 8; ++g) t += xs[g * LL + c];
        } else {
            #pragma unroll
            for (int g = 0; g < 8; ++g) t += xs[200 + g * LL + (c - LL)];
        }
        part[blockIdx.x * 50 + c] = t;
    }
}

// ---------------------------------------------------------------------------
// eval_mono (R13): one block per (bx, k); all 25 l's; register accumulation;
// direct out write. LDS: full per-k packed-weight set, 25 slabs of WSP dwords:
//   [0:4) w1p [4:8) b1p [8:40) w2p [40:44) b2p [44:68) w3p [68:71) b3p [71:74) w4p
//   pair p of array A holds (A[2p], A[2p+1]).
// ---------------------------------------------------------------------------
__global__ __launch_bounds__(256) void eval_mono_kernel(
    const float* __restrict__ xT,
    const float* __restrict__ W1, const float* __restrict__ b1,
    const float* __restrict__ W2, const float* __restrict__ b2,
    const float* __restrict__ W3, const float* __restrict__ b3,
    const float* __restrict__ W4, const float* __restrict__ b4,
    const float* __restrict__ alpha,
    const float* __restrict__ part,
    const float* __restrict__ gamma,
    const float* __restrict__ bn_bias,
    const float* __restrict__ beta,
    float* __restrict__ out)
{
    __shared__ h2v   wl[LL * WSP];          // 2000 dwords = 8 KB
    __shared__ float sss[2 * LL];           // scale[25], shift[25]
    __shared__ float sab[2 * LL];           // alpha_col[25], b4_row[25]
    __shared__ float tmp[2 * LL];           // 50 column partials

    const int tid   = threadIdx.x;
    const int k     = blockIdx.y;
    const int kbase = k * LL;
    const int b     = (blockIdx.x * EVT + tid) * VB;

    // ---- stats partials (threads 0..49; coalesced across lanes per i) ----
    if (tid < 2 * LL) {
        float s = 0.f;
        #pragma unroll
        for (int i = 0; i < PREPB; ++i)
            s += part[i * 50 + tid];
        tmp[tid] = s;
    }
    // ---- alpha column + b4 row (threads 100..124) ----
    if (tid >= 100 && tid < 100 + LL) {
        const int l = tid - 100;
        sab[l]      = alpha[l * KK + k];
        sab[LL + l] = b4[kbase + l];
    }

    // ---- stage packed weights for ALL 25 l's ----
    {   // W2: 800 pairs (contiguous 1600 floats for this k)
        const float* src = W2 + (size_t)kbase * 64;
        for (int idx = tid; idx < 800; idx += EVT) {
            const int l = idx >> 5, p = idx & 31;
            const float2 v = *(const float2*)&src[2 * idx];
            wl[l * WSP + 8 + p] = pack2(v.x, v.y);
        }
    }
    {   // W3: 600 pairs
        const float* src = W3 + (size_t)kbase * 48;
        for (int idx = tid; idx < 600; idx += EVT) {
            const int l = idx / 24, p = idx - l * 24;
            const float2 v = *(const float2*)&src[2 * idx];
            wl[l * WSP + 44 + p] = pack2(v.x, v.y);
        }
    }
    if (tid < 100) {                        // w1p, b1p, b2p: 100 pairs each
        const int l = tid >> 2, p = tid & 3;
        const float2 v1 = *(const float2*)&W1[kbase * 8 + 2 * tid];
        const float2 u1 = *(const float2*)&b1[kbase * 8 + 2 * tid];
        const float2 u2 = *(const float2*)&b2[kbase * 8 + 2 * tid];
        wl[l * WSP +      p] = pack2(v1.x, v1.y);
        wl[l * WSP +  4 + p] = pack2(u1.x, u1.y);
        wl[l * WSP + 40 + p] = pack2(u2.x, u2.y);
    }
    if (tid >= 128 && tid < 128 + 75) {     // b3p, w4p: 75 pairs each
        const int idx = tid - 128;
        const int l = idx / 3, p = idx - 3 * l;
        const float2 u3 = *(const float2*)&b3[kbase * 6 + 2 * idx];
        const float2 v4 = *(const float2*)&W4[kbase * 6 + 2 * idx];
        wl[l * WSP + 68 + p] = pack2(u3.x, u3.y);
        wl[l * WSP + 71 + p] = pack2(v4.x, v4.y);
    }
    __syncthreads();

    if (tid < LL) {
        const float s = tmp[tid], s2 = tmp[LL + tid];
        const float inv_b = 1.f / (float)BATCH;
        const float mean  = s * inv_b;
        const float var   = fmaf(s2, inv_b, -mean * mean);
        const float scale = rsqrtf(var + BN_EPS) * gamma[tid];
        sss[tid]      = scale;
        sss[LL + tid] = fmaf(-mean, scale, bn_bias[tid]);
    }
    __syncthreads();

    // ---- compute (packed fp16, op_sel weight broadcast), all 25 l's ----
    h2v zero2; zero2.x = (_Float16)0.f; zero2.y = (_Float16)0.f;
    float acc[VB] = {0.f, 0.f, 0.f, 0.f};

    #pragma unroll 5
    for (int l = 0; l < LL; ++l) {
        const h2v* w = wl + l * WSP;

        const float scale = sss[l];
        const float shift = sss[LL + l];
        const float a     = sab[l];
        const float b4f   = sab[LL + l];

        const float4 xv = *(const float4*)&xT[l * BATCH + b];
        h2v xn0, xn1;
        xn0.x = (_Float16)fmaf(xv.x, scale, shift);
        xn0.y = (_Float16)fmaf(xv.y, scale, shift);
        xn1.x = (_Float16)fmaf(xv.z, scale, shift);
        xn1.y = (_Float16)fmaf(xv.w, scale, shift);

        // layer 1: 1 -> 8  (w1p[p]=(w1[2p],w1[2p+1]), b1p same)
        h2v h1a[8], h1b[8];
        #pragma unroll
        for (int p = 0; p < 4; ++p) {
            const h2v wp = w[p], bp = w[4 + p];
            h1a[2*p]   = pk_max(pk_fma_wl_cl(xn0, wp, bp), zero2);
            h1a[2*p+1] = pk_max(pk_fma_wh_ch(xn0, wp, bp), zero2);
            h1b[2*p]   = pk_max(pk_fma_wl_cl(xn1, wp, bp), zero2);
            h1b[2*p+1] = pk_max(pk_fma_wh_ch(xn1, wp, bp), zero2);
        }

        // layer 2: 8 -> 8  (w2p[i*4+hp]=(w2[i*8+2hp], w2[i*8+2hp+1]))
        h2v h2a[8], h2b[8];
        #pragma unroll
        for (int i = 0; i < 8; ++i) {
            const h2v bp = w[40 + (i >> 1)];
            const h2v w0 = w[8 + i * 4];
            h2v t0, t1;
            if (i & 1) { t0 = pk_fma_wl_ch(h1a[0], w0, bp);
                         t1 = pk_fma_wl_ch(h1b[0], w0, bp); }
            else       { t0 = pk_fma_wl_cl(h1a[0], w0, bp);
                         t1 = pk_fma_wl_cl(h1b[0], w0, bp); }
            t0 = pk_fma_wh(h1a[1], w0, t0);
            t1 = pk_fma_wh(h1b[1], w0, t1);
            #pragma unroll
            for (int hp = 1; hp < 4; ++hp) {
                const h2v wp = w[8 + i * 4 + hp];
                t0 = pk_fma_wl(h1a[2*hp],   wp, t0);
                t1 = pk_fma_wl(h1b[2*hp],   wp, t1);
                t0 = pk_fma_wh(h1a[2*hp+1], wp, t0);
                t1 = pk_fma_wh(h1b[2*hp+1], wp, t1);
            }
            h2a[i] = pk_max(t0, zero2);
            h2b[i] = pk_max(t1, zero2);
        }

        // layer 3: 8 -> 6  (w3p[jj*4+ip])
        h2v h3a[6], h3b[6];
        #pragma unroll
        for (int jj = 0; jj < 6; ++jj) {
            const h2v bp = w[68 + (jj >> 1)];
            const h2v w0 = w[44 + jj * 4];
            h2v t0, t1;
            if (jj & 1) { t0 = pk_fma_wl_ch(h2a[0], w0, bp);
                          t1 = pk_fma_wl_ch(h2b[0], w0, bp); }
            else        { t0 = pk_fma_wl_cl(h2a[0], w0, bp);
                          t1 = pk_fma_wl_cl(h2b[0], w0, bp); }
            t0 = pk_fma_wh(h2a[1], w0, t0);
            t1 = pk_fma_wh(h2b[1], w0, t1);
            #pragma unroll
            for (int ip = 1; ip < 4; ++ip) {
                const h2v wp = w[44 + jj * 4 + ip];
                t0 = pk_fma_wl(h2a[2*ip],   wp, t0);
                t1 = pk_fma_wl(h2b[2*ip],   wp, t1);
                t0 = pk_fma_wh(h2a[2*ip+1], wp, t0);
                t1 = pk_fma_wh(h2b[2*ip+1], wp, t1);
            }
            h3a[jj] = pk_max(t0, zero2);
            h3b[jj] = pk_max(t1, zero2);
        }

        // layer 4: 6 -> 1 (w4p[jp]=(w4[2jp],w4[2jp+1])), finish in fp32
        h2v fd0 = zero2, fd1 = zero2;
        #pragma unroll
        for (int jp = 0; jp < 3; ++jp) {
            const h2v wp = w[71 + jp];
            fd0 = pk_fma_wl(h3a[2*jp],   wp, fd0);
            fd1 = pk_fma_wl(h3b[2*jp],   wp, fd1);
            fd0 = pk_fma_wh(h3a[2*jp+1], wp, fd0);
            fd1 = pk_fma_wh(h3b[2*jp+1], wp, fd1);
        }
        acc[0] = fmaf(a, b4f + (float)fd0.x, acc[0]);
        acc[1] = fmaf(a, b4f + (float)fd0.y, acc[1]);
        acc[2] = fmaf(a, b4f + (float)fd1.x, acc[2]);
        acc[3] = fmaf(a, b4f + (float)fd1.y, acc[3]);
    }

    const float bk = beta[k];
    float* dst = out + (size_t)b * KK + k;
    dst[0]      = bk + acc[0];
    dst[KK]     = bk + acc[1];
    dst[2 * KK] = bk + acc[2];
    dst[3 * KK] = bk + acc[3];
}

// ---------------------------------------------------------------------------
// fallbacks (small workspace) — fp32, proven correct.
// ---------------------------------------------------------------------------
__device__ __forceinline__ float mlp_eval(
    float xn, int kl,
    const float* __restrict__ W1, const float* __restrict__ b1,
    const float* __restrict__ W2, const float* __restrict__ b2,
    const float* __restrict__ W3, const float* __restrict__ b3,
    const float* __restrict__ W4, const float* __restrict__ b4)
{
    const float* w1  = W1 + kl * 8;
    const float* bb1 = b1 + kl * 8;
    float h1[8];
    #pragma unroll
    for (int h = 0; h < 8; ++h)
        h1[h] = fmaxf(fmaf(xn, w1[h], bb1[h]), 0.f);

    const float* w2  = W2 + kl * 64;
    const float* bb2 = b2 + kl * 8;
    float h2v_[8];
    #pragma unroll
    for (int i = 0; i < 8; ++i) {
        float t = bb2[i];
        #pragma unroll
        for (int h = 0; h < 8; ++h)
            t = fmaf(h1[h], w2[i * 8 + h], t);
        h2v_[i] = fmaxf(t, 0.f);
    }

    const float* w3  = W3 + kl * 48;
    const float* bb3 = b3 + kl * 6;
    float h3[6];
    #pragma unroll
    for (int j = 0; j < 6; ++j) {
        float t = bb3[j];
        #pragma unroll
        for (int i = 0; i < 8; ++i)
            t = fmaf(h2v_[i], w3[j * 8 + i], t);
        h3[j] = fmaxf(t, 0.f);
    }

    const float* w4 = W4 + kl * 6;
    float f = b4[kl];
    #pragma unroll
    for (int j = 0; j < 6; ++j)
        f = fmaf(h3[j], w4[j], f);
    return f;
}

__global__ __launch_bounds__(256) void stats_small_kernel(
    const float* __restrict__ x,
    const float* __restrict__ gamma,
    const float* __restrict__ bn_bias,
    float* __restrict__ ws)
{
    const int l   = blockIdx.x;
    const int tid = threadIdx.x;

    float s = 0.f, s2 = 0.f;
    for (int b = tid; b < BATCH; b += 256) {
        float v = x[b * LL + l];
        s  += v;
        s2  = fmaf(v, v, s2);
    }
    for (int off = 32; off > 0; off >>= 1) {
        s  += __shfl_down(s,  off);
        s2 += __shfl_down(s2, off);
    }
    __shared__ float red[8];
    const int wave = tid >> 6;
    if ((tid & 63) == 0) { red[wave] = s; red[4 + wave] = s2; }
    __syncthreads();
    if (tid == 0) {
        s  = red[0] + red[1] + red[2] + red[3];
        s2 = red[4] + red[5] + red[6] + red[7];
        const float inv_b = 1.f / (float)BATCH;
        float mean = s * inv_b;
        float var  = fmaf(s2, inv_b, -mean * mean);
        float scale = rsqrtf(var + BN_EPS) * gamma[l];
        ws[WS_SCALE + l] = scale;
        ws[WS_SHIFT + l] = fmaf(-mean, scale, bn_bias[l]);
    }
}

__global__ __launch_bounds__(256) void mlp_lds_direct_kernel(
    const float* __restrict__ x,
    const float* __restrict__ W1, const float* __restrict__ b1,
    const float* __restrict__ W2, const float* __restrict__ b2,
    const float* __restrict__ W3, const float* __restrict__ b3,
    const float* __restrict__ W4, const float* __restrict__ b4,
    const float* __restrict__ alpha, const float* __restrict__ beta,
    const float* __restrict__ ws,
    float* __restrict__ out)
{
    __shared__ float xs[256 * LL];
    const int tid = threadIdx.x;
    const int k   = blockIdx.y;
    const int b0  = blockIdx.x * 256;

    const float* xsrc = x + (size_t)b0 * LL;
    #pragma unroll
    for (int i = 0; i < LL; ++i)
        xs[i * 256 + tid] = xsrc[i * 256 + tid];
    __syncthreads();

    float acc = beta[k];
    for (int l = 0; l < LL; ++l) {
        const int kl = k * LL + l;
        const float xn = fmaf(xs[tid * LL + l], ws[WS_SCALE + l], ws[WS_SHIFT + l]);
        const float f  = mlp_eval(xn, kl, W1, b1, W2, b2, W3, b3, W4, b4);
        acc = fmaf(alpha[l * KK + k], f, acc);
    }
    out[(size_t)(b0 + tid) * KK + k] = acc;
}

extern "C" void kernel_launch(void* const* d_in, const int* in_sizes, int n_in,
                              void* d_out, int out_size, void* d_ws, size_t ws_size,
                              hipStream_t stream) {
    const float* x       = (const float*)d_in[0];
    const float* gamma   = (const float*)d_in[1];
    const float* bn_bias = (const float*)d_in[2];
    const float* W1      = (const float*)d_in[3];
    const float* b1      = (const float*)d_in[4];
    const float* W2      = (const float*)d_in[5];
    const float* b2      = (const float*)d_in[6];
    const float* W3      = (const float*)d_in[7];
    const float* b3      = (const float*)d_in[8];
    const float* W4      = (const float*)d_in[9];
    const float* b4      = (const float*)d_in[10];
    const float* alpha   = (const float*)d_in[11];
    const float* beta    = (const float*)d_in[12];

    float* out = (float*)d_out;
    float* ws  = (float*)d_ws;
    float* xT  = ws + WS_XT;

    const bool fast = ws_size >= (size_t)WS_END * sizeof(float);

    if (fast) {
        prep_kernel<<<dim3(PREPB), dim3(256), 0, stream>>>(x, xT, ws + WS_PART);
        eval_mono_kernel<<<dim3(NBX, KK), dim3(EVT), 0, stream>>>(
            xT, W1, b1, W2, b2, W3, b3, W4, b4, alpha,
            ws + WS_PART, gamma, bn_bias, beta, out);
    } else {
        stats_small_kernel<<<dim3(LL), dim3(256), 0, stream>>>(x, gamma, bn_bias, ws);
        mlp_lds_direct_kernel<<<dim3(BATCH / 256, KK), dim3(256), 0, stream>>>(
            x, W1, b1, W2, b2, W3, b3, W4, b4, alpha, beta, ws, out);
    }
}

// Round 4
// 101.549 us; speedup vs baseline: 1.8040x; 1.2864x over previous
//
#include <hip/hip_runtime.h>

// Problem constants (match reference)
#define BATCH  8192
#define KK     25
#define LL     25
#define BN_EPS 1e-5f
#define PREPB  32              // prep blocks (256 rows each) — R6 proven
#define VB     4               // batch elements per thread in eval
#define EVT    256             // eval block threads (4 waves)
#define CHUNK  256             // batch elems per eval block (64 lanes * VB)
#define NBX    (BATCH / CHUNK) // 32 batch-blocks -> grid 32x25=800 blocks
#define WSP    80              // per-l LDS packed-weight slab stride (dwords)

// Workspace layout (float offsets):
#define WS_PART   0                         // [PREPB][50] partial sums
#define WS_SCALE  1600                      // (fallback path only)
#define WS_SHIFT  1632
#define WS_XT     2048                      // [LL][BATCH] transposed x
#define WS_END    (WS_XT + LL * BATCH)

// Packed fp16 pair in one VGPR: weights stored as (w[2p], w[2p+1]) — two
// DIFFERENT weights per dword — broadcast per-half via VOP3P op_sel (R10).
// R14: mono-eval with IN-BLOCK L-SPLIT. R13's fused structure (no reduce
// dispatch, no fp round-trip, no fence) starved parallelism: 200 blocks =
// 800 waves = <1 wave/SIMD -> 8% occupancy, 87% stall. Now each 4-wave block
// owns a 256-batch chunk; wave w computes l in {0-5,6-11,12-17,18-24}; accs
// are summed across waves via 3KB LDS; wave 0 writes out. 800 blocks x 4
// waves = 3200 waves = 12.5/CU, all CUs covered, serial depth 25 -> 6/7.
typedef _Float16 h2v __attribute__((ext_vector_type(2)));

// d.lane = fma(a.lane, w.lo, c.lane)
static __device__ __forceinline__ h2v pk_fma_wl(h2v a, h2v w, h2v c) {
    h2v d;
    asm("v_pk_fma_f16 %0, %1, %2, %3 op_sel:[0,0,0] op_sel_hi:[1,0,1]"
        : "=v"(d) : "v"(a), "v"(w), "v"(c));
    return d;
}
// d.lane = fma(a.lane, w.hi, c.lane)
static __device__ __forceinline__ h2v pk_fma_wh(h2v a, h2v w, h2v c) {
    h2v d;
    asm("v_pk_fma_f16 %0, %1, %2, %3 op_sel:[0,1,0] op_sel_hi:[1,1,1]"
        : "=v"(d) : "v"(a), "v"(w), "v"(c));
    return d;
}
// d.lane = fma(a.lane, w.lo, c.lo)
static __device__ __forceinline__ h2v pk_fma_wl_cl(h2v a, h2v w, h2v c) {
    h2v d;
    asm("v_pk_fma_f16 %0, %1, %2, %3 op_sel:[0,0,0] op_sel_hi:[1,0,0]"
        : "=v"(d) : "v"(a), "v"(w), "v"(c));
    return d;
}
// d.lane = fma(a.lane, w.lo, c.hi)
static __device__ __forceinline__ h2v pk_fma_wl_ch(h2v a, h2v w, h2v c) {
    h2v d;
    asm("v_pk_fma_f16 %0, %1, %2, %3 op_sel:[0,0,1] op_sel_hi:[1,0,1]"
        : "=v"(d) : "v"(a), "v"(w), "v"(c));
    return d;
}
// d.lane = fma(a.lane, w.hi, c.hi)
static __device__ __forceinline__ h2v pk_fma_wh_ch(h2v a, h2v w, h2v c) {
    h2v d;
    asm("v_pk_fma_f16 %0, %1, %2, %3 op_sel:[0,1,1] op_sel_hi:[1,1,1]"
        : "=v"(d) : "v"(a), "v"(w), "v"(c));
    return d;
}
static __device__ __forceinline__ h2v pk_max(h2v a, h2v b) {
    h2v d;
    asm("v_pk_max_f16 %0, %1, %2" : "=v"(d) : "v"(a), "v"(b));
    return d;
}
static __device__ __forceinline__ h2v pack2(float a, float b) {
    h2v r; r.x = (_Float16)a; r.y = (_Float16)b; return r;
}

// One l-iteration of the packed-fp16 MLP (R10 body, verbatim math).
static __device__ __forceinline__ void mlp_iter(
    const h2v* __restrict__ w, float scale, float shift,
    float a, float b4f, float4 xv, h2v zero2, float acc[VB])
{
    h2v xn0, xn1;
    xn0.x = (_Float16)fmaf(xv.x, scale, shift);
    xn0.y = (_Float16)fmaf(xv.y, scale, shift);
    xn1.x = (_Float16)fmaf(xv.z, scale, shift);
    xn1.y = (_Float16)fmaf(xv.w, scale, shift);

    // layer 1: 1 -> 8  (w1p[p]=(w1[2p],w1[2p+1]), b1p same)
    h2v h1a[8], h1b[8];
    #pragma unroll
    for (int p = 0; p < 4; ++p) {
        const h2v wp = w[p], bp = w[4 + p];
        h1a[2*p]   = pk_max(pk_fma_wl_cl(xn0, wp, bp), zero2);
        h1a[2*p+1] = pk_max(pk_fma_wh_ch(xn0, wp, bp), zero2);
        h1b[2*p]   = pk_max(pk_fma_wl_cl(xn1, wp, bp), zero2);
        h1b[2*p+1] = pk_max(pk_fma_wh_ch(xn1, wp, bp), zero2);
    }

    // layer 2: 8 -> 8  (w2p[i*4+hp]=(w2[i*8+2hp], w2[i*8+2hp+1]))
    h2v h2a[8], h2b[8];
    #pragma unroll
    for (int i = 0; i < 8; ++i) {
        const h2v bp = w[40 + (i >> 1)];
        const h2v w0 = w[8 + i * 4];
        h2v t0, t1;
        if (i & 1) { t0 = pk_fma_wl_ch(h1a[0], w0, bp);
                     t1 = pk_fma_wl_ch(h1b[0], w0, bp); }
        else       { t0 = pk_fma_wl_cl(h1a[0], w0, bp);
                     t1 = pk_fma_wl_cl(h1b[0], w0, bp); }
        t0 = pk_fma_wh(h1a[1], w0, t0);
        t1 = pk_fma_wh(h1b[1], w0, t1);
        #pragma unroll
        for (int hp = 1; hp < 4; ++hp) {
            const h2v wp = w[8 + i * 4 + hp];
            t0 = pk_fma_wl(h1a[2*hp],   wp, t0);
            t1 = pk_fma_wl(h1b[2*hp],   wp, t1);
            t0 = pk_fma_wh(h1a[2*hp+1], wp, t0);
            t1 = pk_fma_wh(h1b[2*hp+1], wp, t1);
        }
        h2a[i] = pk_max(t0, zero2);
        h2b[i] = pk_max(t1, zero2);
    }

    // layer 3: 8 -> 6  (w3p[jj*4+ip])
    h2v h3a[6], h3b[6];
    #pragma unroll
    for (int jj = 0; jj < 6; ++jj) {
        const h2v bp = w[68 + (jj >> 1)];
        const h2v w0 = w[44 + jj * 4];
        h2v t0, t1;
        if (jj & 1) { t0 = pk_fma_wl_ch(h2a[0], w0, bp);
                      t1 = pk_fma_wl_ch(h2b[0], w0, bp); }
        else        { t0 = pk_fma_wl_cl(h2a[0], w0, bp);
                      t1 = pk_fma_wl_cl(h2b[0], w0, bp); }
        t0 = pk_fma_wh(h2a[1], w0, t0);
        t1 = pk_fma_wh(h2b[1], w0, t1);
        #pragma unroll
        for (int ip = 1; ip < 4; ++ip) {
            const h2v wp = w[44 + jj * 4 + ip];
            t0 = pk_fma_wl(h2a[2*ip],   wp, t0);
            t1 = pk_fma_wl(h2b[2*ip],   wp, t1);
            t0 = pk_fma_wh(h2a[2*ip+1], wp, t0);
            t1 = pk_fma_wh(h2b[2*ip+1], wp, t1);
        }
        h3a[jj] = pk_max(t0, zero2);
        h3b[jj] = pk_max(t1, zero2);
    }

    // layer 4: 6 -> 1 (w4p[jp]=(w4[2jp],w4[2jp+1])), finish in fp32
    h2v fd0 = zero2, fd1 = zero2;
    #pragma unroll
    for (int jp = 0; jp < 3; ++jp) {
        const h2v wp = w[71 + jp];
        fd0 = pk_fma_wl(h3a[2*jp],   wp, fd0);
        fd1 = pk_fma_wl(h3b[2*jp],   wp, fd1);
        fd0 = pk_fma_wh(h3a[2*jp+1], wp, fd0);
        fd1 = pk_fma_wh(h3b[2*jp+1], wp, fd1);
    }
    acc[0] = fmaf(a, b4f + (float)fd0.x, acc[0]);
    acc[1] = fmaf(a, b4f + (float)fd0.y, acc[1]);
    acc[2] = fmaf(a, b4f + (float)fd1.x, acc[2]);
    acc[3] = fmaf(a, b4f + (float)fd1.y, acc[3]);
}

// ---------------------------------------------------------------------------
// prep: coalesced read of x chunk -> LDS; coalesced transposed write to xT;
// per-column partial sum/sumsq (no atomics). 32 blocks x 256 rows. (R6 verbatim)
// ---------------------------------------------------------------------------
__global__ __launch_bounds__(256) void prep_kernel(
    const float* __restrict__ x,
    float* __restrict__ xT,
    float* __restrict__ part)
{
    __shared__ float xs[256 * LL];          // 25.6 KB
    const int tid = threadIdx.x;
    const int b0  = blockIdx.x * 256;

    const float* src = x + (size_t)b0 * LL;
    #pragma unroll
    for (int i = 0; i < LL; ++i)
        xs[i * 256 + tid] = src[i * 256 + tid];
    __syncthreads();

    #pragma unroll
    for (int l = 0; l < LL; ++l)
        xT[l * BATCH + b0 + tid] = xs[tid * LL + l];

    float s = 0.f, s2 = 0.f;
    if (tid < 200) {
        const int l = tid % LL;
        const int g = tid / LL;
        #pragma unroll
        for (int r = 0; r < 32; ++r) {
            const float v = xs[(g * 32 + r) * LL + l];
            s += v;
            s2 = fmaf(v, v, s2);
        }
    }
    __syncthreads();
    if (tid < 200) { xs[tid] = s; xs[200 + tid] = s2; }
    __syncthreads();

    if (tid < 50) {
        const int c = tid;
        float t = 0.f;
        if (c < LL) {
            #pragma unroll
            for (int g = 0; g < 8; ++g) t += xs[g * LL + c];
        } else {
            #pragma unroll
            for (int g = 0; g < 8; ++g) t += xs[200 + g * LL + (c - LL)];
        }
        part[blockIdx.x * 50 + c] = t;
    }
}

// ---------------------------------------------------------------------------
// eval_mono4 (R14): one block per (bx, k); 4 waves split the 25 l's
// {0-5, 6-11, 12-17, 18-24}; LDS cross-wave acc reduction; direct out write.
// LDS weight slab per l (stride WSP=80 dwords):
//   [0:4) w1p [4:8) b1p [8:40) w2p [40:44) b2p [44:68) w3p [68:71) b3p [71:74) w4p
//   pair p of array A holds (A[2p], A[2p+1]).
// ---------------------------------------------------------------------------
__global__ __launch_bounds__(256) void eval_mono4_kernel(
    const float* __restrict__ xT,
    const float* __restrict__ W1, const float* __restrict__ b1,
    const float* __restrict__ W2, const float* __restrict__ b2,
    const float* __restrict__ W3, const float* __restrict__ b3,
    const float* __restrict__ W4, const float* __restrict__ b4,
    const float* __restrict__ alpha,
    const float* __restrict__ part,
    const float* __restrict__ gamma,
    const float* __restrict__ bn_bias,
    const float* __restrict__ beta,
    float* __restrict__ out)
{
    __shared__ h2v   wl[LL * WSP];          // 2000 dwords = 8 KB
    __shared__ float sss[2 * LL];           // scale[25], shift[25]
    __shared__ float sab[2 * LL];           // alpha_col[25], b4_row[25]
    __shared__ float tmp[2 * LL];           // 50 column partials
    __shared__ float red[3][64][VB];        // waves 1-3 partial accs (3 KB)

    const int tid   = threadIdx.x;
    const int w     = tid >> 6;             // wave id 0..3
    const int lane  = tid & 63;
    const int k     = blockIdx.y;
    const int kbase = k * LL;
    const int b     = blockIdx.x * CHUNK + lane * VB;

    // ---- stats partials (threads 0..49; coalesced across lanes per i) ----
    if (tid < 2 * LL) {
        float s = 0.f;
        #pragma unroll
        for (int i = 0; i < PREPB; ++i)
            s += part[i * 50 + tid];
        tmp[tid] = s;
    }
    // ---- alpha column + b4 row (threads 100..124) ----
    if (tid >= 100 && tid < 100 + LL) {
        const int l = tid - 100;
        sab[l]      = alpha[l * KK + k];
        sab[LL + l] = b4[kbase + l];
    }

    // ---- stage packed weights for ALL 25 l's ----
    {   // W2: 800 pairs (contiguous 1600 floats for this k)
        const float* src = W2 + (size_t)kbase * 64;
        for (int idx = tid; idx < 800; idx += EVT) {
            const int l = idx >> 5, p = idx & 31;
            const float2 v = *(const float2*)&src[2 * idx];
            wl[l * WSP + 8 + p] = pack2(v.x, v.y);
        }
    }
    {   // W3: 600 pairs
        const float* src = W3 + (size_t)kbase * 48;
        for (int idx = tid; idx < 600; idx += EVT) {
            const int l = idx / 24, p = idx - l * 24;
            const float2 v = *(const float2*)&src[2 * idx];
            wl[l * WSP + 44 + p] = pack2(v.x, v.y);
        }
    }
    if (tid < 100) {                        // w1p, b1p, b2p: 100 pairs each
        const int l = tid >> 2, p = tid & 3;
        const float2 v1 = *(const float2*)&W1[kbase * 8 + 2 * tid];
        const float2 u1 = *(const float2*)&b1[kbase * 8 + 2 * tid];
        const float2 u2 = *(const float2*)&b2[kbase * 8 + 2 * tid];
        wl[l * WSP +      p] = pack2(v1.x, v1.y);
        wl[l * WSP +  4 + p] = pack2(u1.x, u1.y);
        wl[l * WSP + 40 + p] = pack2(u2.x, u2.y);
    }
    if (tid >= 128 && tid < 128 + 75) {     // b3p, w4p: 75 pairs each
        const int idx = tid - 128;
        const int l = idx / 3, p = idx - 3 * l;
        const float2 u3 = *(const float2*)&b3[kbase * 6 + 2 * idx];
        const float2 v4 = *(const float2*)&W4[kbase * 6 + 2 * idx];
        wl[l * WSP + 68 + p] = pack2(u3.x, u3.y);
        wl[l * WSP + 71 + p] = pack2(v4.x, v4.y);
    }
    __syncthreads();

    if (tid < LL) {
        const float s = tmp[tid], s2 = tmp[LL + tid];
        const float inv_b = 1.f / (float)BATCH;
        const float mean  = s * inv_b;
        const float var   = fmaf(s2, inv_b, -mean * mean);
        const float scale = rsqrtf(var + BN_EPS) * gamma[tid];
        sss[tid]      = scale;
        sss[LL + tid] = fmaf(-mean, scale, bn_bias[tid]);
    }
    __syncthreads();

    // ---- compute: wave w handles l in [6w, 6w+6) (+ l=24 for wave 3) ----
    h2v zero2; zero2.x = (_Float16)0.f; zero2.y = (_Float16)0.f;
    float acc[VB] = {0.f, 0.f, 0.f, 0.f};
    const int lbase = w * 6;

    #pragma unroll
    for (int i = 0; i < 6; ++i) {
        const int l = lbase + i;
        mlp_iter(wl + l * WSP, sss[l], sss[LL + l], sab[l], sab[LL + l],
                 *(const float4*)&xT[l * BATCH + b], zero2, acc);
    }
    if (w == 3) {
        mlp_iter(wl + 24 * WSP, sss[24], sss[LL + 24], sab[24], sab[LL + 24],
                 *(const float4*)&xT[24 * BATCH + b], zero2, acc);
    }

    // ---- cross-wave reduction in LDS; wave 0 writes out ----
    if (w > 0) {
        #pragma unroll
        for (int q = 0; q < VB; ++q)
            red[w - 1][lane][q] = acc[q];
    }
    __syncthreads();
    if (w == 0) {
        const float bk = beta[k];
        #pragma unroll
        for (int q = 0; q < VB; ++q) {
            float s = acc[q] + red[0][lane][q] + red[1][lane][q] + red[2][lane][q];
            out[(size_t)(b + q) * KK + k] = bk + s;
        }
    }
}

// ---------------------------------------------------------------------------
// fallbacks (small workspace) — fp32, proven correct.
// ---------------------------------------------------------------------------
__device__ __forceinline__ float mlp_eval(
    float xn, int kl,
    const float* __restrict__ W1, const float* __restrict__ b1,
    const float* __restrict__ W2, const float* __restrict__ b2,
    const float* __restrict__ W3, const float* __restrict__ b3,
    const float* __restrict__ W4, const float* __restrict__ b4)
{
    const float* w1  = W1 + kl * 8;
    const float* bb1 = b1 + kl * 8;
    float h1[8];
    #pragma unroll
    for (int h = 0; h < 8; ++h)
        h1[h] = fmaxf(fmaf(xn, w1[h], bb1[h]), 0.f);

    const float* w2  = W2 + kl * 64;
    const float* bb2 = b2 + kl * 8;
    float h2v_[8];
    #pragma unroll
    for (int i = 0; i < 8; ++i) {
        float t = bb2[i];
        #pragma unroll
        for (int h = 0; h < 8; ++h)
            t = fmaf(h1[h], w2[i * 8 + h], t);
        h2v_[i] = fmaxf(t, 0.f);
    }

    const float* w3  = W3 + kl * 48;
    const float* bb3 = b3 + kl * 6;
    float h3[6];
    #pragma unroll
    for (int j = 0; j < 6; ++j) {
        float t = bb3[j];
        #pragma unroll
        for (int i = 0; i < 8; ++i)
            t = fmaf(h2v_[i], w3[j * 8 + i], t);
        h3[j] = fmaxf(t, 0.f);
    }

    const float* w4 = W4 + kl * 6;
    float f = b4[kl];
    #pragma unroll
    for (int j = 0; j < 6; ++j)
        f = fmaf(h3[j], w4[j], f);
    return f;
}

__global__ __launch_bounds__(256) void stats_small_kernel(
    const float* __restrict__ x,
    const float* __restrict__ gamma,
    const float* __restrict__ bn_bias,
    float* __restrict__ ws)
{
    const int l   = blockIdx.x;
    const int tid = threadIdx.x;

    float s = 0.f, s2 = 0.f;
    for (int b = tid; b < BATCH; b += 256) {
        float v = x[b * LL + l];
        s  += v;
        s2  = fmaf(v, v, s2);
    }
    for (int off = 32; off > 0; off >>= 1) {
        s  += __shfl_down(s,  off);
        s2 += __shfl_down(s2, off);
    }
    __shared__ float red[8];
    const int wave = tid >> 6;
    if ((tid & 63) == 0) { red[wave] = s; red[4 + wave] = s2; }
    __syncthreads();
    if (tid == 0) {
        s  = red[0] + red[1] + red[2] + red[3];
        s2 = red[4] + red[5] + red[6] + red[7];
        const float inv_b = 1.f / (float)BATCH;
        float mean = s * inv_b;
        float var  = fmaf(s2, inv_b, -mean * mean);
        float scale = rsqrtf(var + BN_EPS) * gamma[l];
        ws[WS_SCALE + l] = scale;
        ws[WS_SHIFT + l] = fmaf(-mean, scale, bn_bias[l]);
    }
}

__global__ __launch_bounds__(256) void mlp_lds_direct_kernel(
    const float* __restrict__ x,
    const float* __restrict__ W1, const float* __restrict__ b1,
    const float* __restrict__ W2, const float* __restrict__ b2,
    const float* __restrict__ W3, const float* __restrict__ b3,
    const float* __restrict__ W4, const float* __restrict__ b4,
    const float* __restrict__ alpha, const float* __restrict__ beta,
    const float* __restrict__ ws,
    float* __restrict__ out)
{
    __shared__ float xs[256 * LL];
    const int tid = threadIdx.x;
    const int k   = blockIdx.y;
    const int b0  = blockIdx.x * 256;

    const float* xsrc = x + (size_t)b0 * LL;
    #pragma unroll
    for (int i = 0; i < LL; ++i)
        xs[i * 256 + tid] = xsrc[i * 256 + tid];
    __syncthreads();

    float acc = beta[k];
    for (int l = 0; l < LL; ++l) {
        const int kl = k * LL + l;
        const float xn = fmaf(xs[tid * LL + l], ws[WS_SCALE + l], ws[WS_SHIFT + l]);
        const float f  = mlp_eval(xn, kl, W1, b1, W2, b2, W3, b3, W4, b4);
        acc = fmaf(alpha[l * KK + k], f, acc);
    }
    out[(size_t)(b0 + tid) * KK + k] = acc;
}

extern "C" void kernel_launch(void* const* d_in, const int* in_sizes, int n_in,
                              void* d_out, int out_size, void* d_ws, size_t ws_size,
                              hipStream_t stream) {
    const float* x       = (const float*)d_in[0];
    const float* gamma   = (const float*)d_in[1];
    const float* bn_bias = (const float*)d_in[2];
    const float* W1      = (const float*)d_in[3];
    const float* b1      = (const float*)d_in[4];
    const float* W2      = (const float*)d_in[5];
    const float* b2      = (const float*)d_in[6];
    const float* W3      = (const float*)d_in[7];
    const float* b3      = (const float*)d_in[8];
    const float* W4      = (const float*)d_in[9];
    const float* b4      = (const float*)d_in[10];
    const float* alpha   = (const float*)d_in[11];
    const float* beta    = (const float*)d_in[12];

    float* out = (float*)d_out;
    float* ws  = (float*)d_ws;
    float* xT  = ws + WS_XT;

    const bool fast = ws_size >= (size_t)WS_END * sizeof(float);

    if (fast) {
        prep_kernel<<<dim3(PREPB), dim3(256), 0, stream>>>(x, xT, ws + WS_PART);
        eval_mono4_kernel<<<dim3(NBX, KK), dim3(EVT), 0, stream>>>(
            xT, W1, b1, W2, b2, W3, b3, W4, b4, alpha,
            ws + WS_PART, gamma, bn_bias, beta, out);
    } else {
        stats_small_kernel<<<dim3(LL), dim3(256), 0, stream>>>(x, gamma, bn_bias, ws);
        mlp_lds_direct_kernel<<<dim3(BATCH / 256, KK), dim3(256), 0, stream>>>(
            x, W1, b1, W2, b2, W3, b3, W4, b4, alpha, beta, ws, out);
    }
}